// Round 7
// baseline (4676.339 us; speedup 1.0000x reference)
//
#include <hip/hip_runtime.h>
#include <hip/hip_bf16.h>

// CPC (CDCK2) round 6: register-resident-weight GRU (512 thr/block, weights in
// 192 VGPRs, h f32 in LDS). MFMA bf16 convs as round 5. Workspace ~155MB.
// B=32, L=40960, CH=512, H=256, T=12; F: 8192/2048/1024/512/256.

using bf16 = __hip_bfloat16;
typedef __attribute__((ext_vector_type(8))) short bf16x8;
typedef __attribute__((ext_vector_type(4))) float f32x4;

__device__ __forceinline__ float bf2f(bf16 v) { return __bfloat162float(v); }
__device__ __forceinline__ bf16 f2bf(float f) { return __float2bfloat16(f); }
__device__ __forceinline__ ushort bfbits(float f) {
  bf16 b = f2bf(f);
  return *reinterpret_cast<ushort*>(&b);
}
union FragU { uint4 u; bf16x8 v; };

// ---------------------------------------------------------------- stats1 (conv1 on the fly, x in LDS)
__global__ __launch_bounds__(256) void stats1_kernel(
    const float* __restrict__ x, const float* __restrict__ w1, float* __restrict__ sums) {
  __shared__ float xs[2576];
  int s = blockIdx.x, b = blockIdx.y;
  const float* xb = x + (size_t)b * 40960;
  int w0 = 2560 * s - 3;
  for (int i = threadIdx.x; i < 2565; i += 256) {
    int xi = w0 + i;
    xs[i] = ((unsigned)xi < 40960u) ? xb[xi] : 0.f;
  }
  __syncthreads();
  int c0 = threadIdx.x, c1 = threadIdx.x + 256;
  float wA[10], wB[10];
#pragma unroll
  for (int k = 0; k < 10; ++k) { wA[k] = w1[c0 * 10 + k]; wB[k] = w1[c1 * 10 + k]; }
  float sA = 0.f, qA = 0.f, sB = 0.f, qB = 0.f;
  for (int f = 0; f < 512; ++f) {
    const float* xp = &xs[5 * f];
    float aA = 0.f, aB = 0.f;
#pragma unroll
    for (int k = 0; k < 10; ++k) {
      float xv = xp[k];
      aA = fmaf(xv, wA[k], aA);
      aB = fmaf(xv, wB[k], aB);
    }
    sA += aA; qA = fmaf(aA, aA, qA);
    sB += aB; qB = fmaf(aB, aB, qB);
  }
  atomicAdd(&sums[c0], sA); atomicAdd(&sums[512 + c0], qA);
  atomicAdd(&sums[c1], sB); atomicAdd(&sums[512 + c1], qB);
}

// ---------------------------------------------------------------- BN stats (bf16 z)
__global__ __launch_bounds__(256) void stats_kernel(
    const bf16* __restrict__ z, int F, float* __restrict__ sums) {
  int bc = blockIdx.x;
  int c = bc & 511;
  const bf16* p = z + (size_t)bc * F;
  float s = 0.f, q = 0.f;
  for (int i = threadIdx.x; i < F; i += 256) {
    float v = bf2f(p[i]);
    s += v;
    q = fmaf(v, v, q);
  }
  __shared__ float rs[256], rq[256];
  rs[threadIdx.x] = s; rq[threadIdx.x] = q;
  __syncthreads();
  for (int w = 128; w > 0; w >>= 1) {
    if (threadIdx.x < w) {
      rs[threadIdx.x] += rs[threadIdx.x + w];
      rq[threadIdx.x] += rq[threadIdx.x + w];
    }
    __syncthreads();
  }
  if (threadIdx.x == 0) {
    atomicAdd(&sums[c], rs[0]);
    atomicAdd(&sums[512 + c], rq[0]);
  }
}

__global__ void finalize_kernel(const float* __restrict__ sums, const float* __restrict__ g,
                                const float* __restrict__ be, float invN,
                                float* __restrict__ ab) {
  int c = threadIdx.x;  // 512
  float mean = sums[c] * invN;
  float var = fmaf(-mean, mean, sums[512 + c] * invN);
  float a = g[c] * rsqrtf(var + 1e-5f);
  ab[c] = a;
  ab[512 + c] = fmaf(-mean, a, be[c]);
}

// ---------------------------------------------------------------- transpose (wih only)
__global__ __launch_bounds__(256) void transpose_kernel(
    const float* __restrict__ in, float* __restrict__ out, int R, int C) {
  __shared__ float t[64][65];
  int c0 = blockIdx.x * 64, r0 = blockIdx.y * 64;
  int tx = threadIdx.x & 63, ty = threadIdx.x >> 6;
  for (int i = ty; i < 64; i += 4) {
    int r = r0 + i, c = c0 + tx;
    t[i][tx] = (r < R && c < C) ? in[(size_t)r * C + c] : 0.f;
  }
  __syncthreads();
  for (int i = ty; i < 64; i += 4) {
    int c = c0 + i, r = r0 + tx;
    if (c < C && r < R) out[(size_t)c * R + r] = t[tx][i];
  }
}

__global__ void cvt_bf16_kernel(const float* __restrict__ in, bf16* __restrict__ out, int n) {
  int i = blockIdx.x * 256 + threadIdx.x;
  if (i < n) out[i] = f2bf(in[i]);
}

// pack whh for register-resident GRU:
// P2[(q*64+cc)*768 + gj] = pack2(whh[gj][128q+2cc], whh[gj][128q+2cc+1])
__global__ void pack_whh_kernel(const float* __restrict__ whh, uint* __restrict__ P2) {
  int idx = blockIdx.x * 256 + threadIdx.x;
  if (idx < 98304) {
    int qcc = idx / 768, gj = idx % 768;
    int q = qcc >> 6, cc = qcc & 63;
    int c0 = 128 * q + 2 * cc;
    float lo = whh[(size_t)gj * 256 + c0];
    float hi = whh[(size_t)gj * 256 + c0 + 1];
    P2[idx] = (uint)bfbits(lo) | ((uint)bfbits(hi) << 16);
  }
}

// ---------------------------------------------------------------- norm1 (conv1+BN1+ReLU -> padded bf16)
__global__ __launch_bounds__(256) void norm1_kernel(
    const float* __restrict__ x, const float* __restrict__ w1,
    const float* __restrict__ ab, bf16* __restrict__ zn, int chunk0) {
  __shared__ float xs[1312];
  int s = blockIdx.x, bl = blockIdx.y;
  int pidx = s * 256 + threadIdx.x;
  const float* xb = x + (size_t)(chunk0 + bl) * 40960;
  int w0 = 1280 * s - 33;
  for (int i = threadIdx.x; i < 1285; i += 256) {
    int xi = w0 + i;
    xs[i] = ((unsigned)xi < 40960u) ? xb[xi] : 0.f;
  }
  __syncthreads();
  if (pidx >= 8208) return;
  int fi = pidx - 6;
  bool inb = ((unsigned)fi < 8192u);
  const float* xp = &xs[5 * threadIdx.x];
  bf16* zp = zn + (size_t)bl * 512 * 8208 + pidx;
  for (int c = 0; c < 512; ++c) {
    float v = 0.f;
    if (inb) {
      float acc = 0.f;
      const float* w = &w1[c * 10];
#pragma unroll
      for (int k = 0; k < 10; ++k) acc = fmaf(xp[k], w[k], acc);
      v = fmaxf(fmaf(ab[c], acc, ab[512 + c]), 0.f);
    }
    zp[(size_t)c * 8208] = f2bf(v);
  }
}

// ---------------------------------------------------------------- conv2 MFMA
__global__ __launch_bounds__(256) void conv2_mfma(
    const bf16* __restrict__ zn, const bf16* __restrict__ wB,
    bf16* __restrict__ out, int chunk0) {
  __shared__ ushort aL[4][520];
  __shared__ ushort bL[128][36];
  int fo0 = blockIdx.x * 128, co0 = blockIdx.y * 128, bl = blockIdx.z;
  int tid = threadIdx.x;
  int w = tid >> 6, l = tid & 63;
  int m0 = (w >> 1) * 64, n0 = (w & 1) * 64;
  int row = l & 15, kq = l >> 4;
  f32x4 acc[4][4];
#pragma unroll
  for (int i = 0; i < 4; ++i)
#pragma unroll
    for (int j = 0; j < 4; ++j) acc[i][j] = {0.f, 0.f, 0.f, 0.f};
  const ushort* zb = (const ushort*)zn + (size_t)bl * 512 * 8208;
  int astart = 4 * fo0 + 4;
  int sco = tid >> 1, shalf = tid & 1;
  for (int step = 0; step < 128; ++step) {
    int ci0 = step * 4;
    int k0 = step * 32;
    __syncthreads();
    for (int u = tid; u < 520; u += 256) {
      int ci = u / 130, off = (u % 130) * 4;
      *(uint2*)&aL[ci][off] =
          *(const uint2*)(zb + (size_t)(ci0 + ci) * 8208 + astart + off);
    }
    {
      const uint2* src = (const uint2*)(wB + (size_t)(co0 + sco) * 4096 + k0 + shalf * 16);
      uint2* dst = (uint2*)&bL[sco][shalf * 16];
      dst[0] = src[0]; dst[1] = src[1]; dst[2] = src[2]; dst[3] = src[3];
    }
    __syncthreads();
    bf16x8 af[4], bfr[4];
#pragma unroll
    for (int mi = 0; mi < 4; ++mi) {
      int am = (m0 + mi * 16 + row) * 4;
      const uint2* ap = (const uint2*)((const char*)&aL[0][0] + kq * 1040 + am * 2);
      uint2 a0 = ap[0], a1 = ap[1];
      FragU f; f.u = make_uint4(a0.x, a0.y, a1.x, a1.y);
      af[mi] = f.v;
    }
#pragma unroll
    for (int ni = 0; ni < 4; ++ni) {
      int col = n0 + ni * 16 + row;
      const uint2* bp = (const uint2*)((const char*)&bL[0][0] + col * 72 + kq * 16);
      uint2 b0 = bp[0], b1 = bp[1];
      FragU f; f.u = make_uint4(b0.x, b0.y, b1.x, b1.y);
      bfr[ni] = f.v;
    }
#pragma unroll
    for (int mi = 0; mi < 4; ++mi)
#pragma unroll
      for (int ni = 0; ni < 4; ++ni)
        acc[mi][ni] = __builtin_amdgcn_mfma_f32_16x16x32_bf16(af[mi], bfr[ni], acc[mi][ni], 0, 0, 0);
  }
  size_t ob = (size_t)(chunk0 + bl) * 512;
#pragma unroll
  for (int mi = 0; mi < 4; ++mi)
#pragma unroll
    for (int ni = 0; ni < 4; ++ni)
#pragma unroll
      for (int r = 0; r < 4; ++r) {
        int m = m0 + mi * 16 + kq * 4 + r;
        int n = n0 + ni * 16 + row;
        out[(ob + co0 + n) * 2048 + fo0 + m] = f2bf(acc[mi][ni][r]);
      }
}

// ---------------------------------------------------------------- convN MFMA (K=4,S=2,P=1; layers 3-5)
__global__ __launch_bounds__(256) void convN_mfma(
    const bf16* __restrict__ in, const bf16* __restrict__ wB,
    const float* __restrict__ ab, bf16* __restrict__ out, int Fi, int Fo) {
  __shared__ ushort aL[8][264];
  __shared__ ushort bL[128][36];
  int fo0 = blockIdx.x * 128, co0 = blockIdx.y * 128, b = blockIdx.z;
  int tid = threadIdx.x;
  int w = tid >> 6, l = tid & 63;
  int m0 = (w >> 1) * 64, n0 = (w & 1) * 64;
  int row = l & 15, kq = l >> 4;
  f32x4 acc[4][4];
#pragma unroll
  for (int i = 0; i < 4; ++i)
#pragma unroll
    for (int j = 0; j < 4; ++j) acc[i][j] = {0.f, 0.f, 0.f, 0.f};
  int fi0 = fo0 * 2 - 1;
  const bf16* ib = in + (size_t)b * 512 * Fi;
  int sco = tid >> 1, shalf = tid & 1;
  for (int step = 0; step < 64; ++step) {
    int ci0 = step * 8;
    int k0 = step * 32;
    __syncthreads();
    for (int u = tid; u < 1032; u += 256) {
      int ci = u / 129, pp = (u % 129) * 2;
      float a = ab[ci0 + ci], bb = ab[512 + ci0 + ci];
      const bf16* zr = ib + (size_t)(ci0 + ci) * Fi;
      uint pk = 0;
#pragma unroll
      for (int e = 0; e < 2; ++e) {
        int fi = fi0 + pp + e;
        float v = 0.f;
        if ((unsigned)fi < (unsigned)Fi)
          v = fmaxf(fmaf(a, bf2f(zr[fi]), bb), 0.f);
        pk |= (uint)bfbits(v) << (16 * e);
      }
      *(uint*)&aL[ci][pp] = pk;
    }
    {
      const uint2* src = (const uint2*)(wB + (size_t)(co0 + sco) * 2048 + k0 + shalf * 16);
      uint2* dst = (uint2*)&bL[sco][shalf * 16];
      dst[0] = src[0]; dst[1] = src[1]; dst[2] = src[2]; dst[3] = src[3];
    }
    __syncthreads();
    bf16x8 af[4], bfr[4];
#pragma unroll
    for (int mi = 0; mi < 4; ++mi) {
      int p0 = (m0 + mi * 16 + row) * 2;
      const char* base = (const char*)&aL[0][0];
      const uint* r0p = (const uint*)(base + (2 * kq) * 528 + p0 * 2);
      const uint* r1p = (const uint*)(base + (2 * kq + 1) * 528 + p0 * 2);
      FragU f; f.u = make_uint4(r0p[0], r0p[1], r1p[0], r1p[1]);
      af[mi] = f.v;
    }
#pragma unroll
    for (int ni = 0; ni < 4; ++ni) {
      int col = n0 + ni * 16 + row;
      const uint2* bp = (const uint2*)((const char*)&bL[0][0] + col * 72 + kq * 16);
      uint2 b0 = bp[0], b1 = bp[1];
      FragU f; f.u = make_uint4(b0.x, b0.y, b1.x, b1.y);
      bfr[ni] = f.v;
    }
#pragma unroll
    for (int mi = 0; mi < 4; ++mi)
#pragma unroll
      for (int ni = 0; ni < 4; ++ni)
        acc[mi][ni] = __builtin_amdgcn_mfma_f32_16x16x32_bf16(af[mi], bfr[ni], acc[mi][ni], 0, 0, 0);
  }
  size_t ob = (size_t)b * 512;
#pragma unroll
  for (int mi = 0; mi < 4; ++mi)
#pragma unroll
    for (int ni = 0; ni < 4; ++ni)
#pragma unroll
      for (int r = 0; r < 4; ++r) {
        int m = m0 + mi * 16 + kq * 4 + r;
        int n = n0 + ni * 16 + row;
        out[(ob + co0 + n) * Fo + fo0 + m] = f2bf(acc[mi][ni][r]);
      }
}

// ---------------------------------------------------------------- gi GEMM (VALU, small)
__global__ __launch_bounds__(256) void gi_kernel(
    const bf16* __restrict__ z5, const float* __restrict__ wihT,
    const float* __restrict__ bih, const float* __restrict__ ab,
    float* __restrict__ gi) {
  __shared__ float a_lds[8][64];
  __shared__ float w_lds[8][128];
  int t0 = blockIdx.x * 64, j0 = blockIdx.y * 128, b = blockIdx.z;
  int tid = threadIdx.x, tx = tid & 15, ty = tid >> 4;
  float acc[4][8] = {};
  for (int ci0 = 0; ci0 < 512; ci0 += 8) {
    __syncthreads();
    for (int i = tid; i < 512; i += 256) {
      int ci = i >> 6, t = i & 63;
      float v = bf2f(z5[((size_t)b * 512 + ci0 + ci) * 256 + t0 + t]);
      a_lds[ci][t] = fmaxf(fmaf(ab[ci0 + ci], v, ab[512 + ci0 + ci]), 0.f);
    }
    {
      int i = tid * 4;
      int ci = i >> 7, j = i & 127;
      *(float4*)&w_lds[ci][j] = *(const float4*)&wihT[(size_t)(ci0 + ci) * 768 + j0 + j];
    }
    __syncthreads();
#pragma unroll
    for (int ci = 0; ci < 8; ++ci) {
      float av[4];
#pragma unroll
      for (int j = 0; j < 4; ++j) av[j] = a_lds[ci][tx + 16 * j];
      const float* wp = &w_lds[ci][ty * 8];
      float4 w0 = *(const float4*)wp;
      float4 w1 = *(const float4*)(wp + 4);
      float wv[8] = {w0.x, w0.y, w0.z, w0.w, w1.x, w1.y, w1.z, w1.w};
#pragma unroll
      for (int j = 0; j < 4; ++j)
#pragma unroll
        for (int cc = 0; cc < 8; ++cc)
          acc[j][cc] = fmaf(av[j], wv[cc], acc[j][cc]);
    }
  }
  float bv[8];
#pragma unroll
  for (int cc = 0; cc < 8; ++cc) bv[cc] = bih[j0 + ty * 8 + cc];
#pragma unroll
  for (int j = 0; j < 4; ++j) {
    int rowi = t0 + tx + 16 * j;
    float4 s0 = {acc[j][0] + bv[0], acc[j][1] + bv[1], acc[j][2] + bv[2], acc[j][3] + bv[3]};
    float4 s1 = {acc[j][4] + bv[4], acc[j][5] + bv[5], acc[j][6] + bv[6], acc[j][7] + bv[7]};
    float* gp = &gi[((size_t)b * 256 + rowi) * 768 + j0 + ty * 8];
    *(float4*)gp = s0;
    *(float4*)(gp + 4) = s1;
  }
}

// ---------------------------------------------------------------- GRU v2
// 32 blocks x 512 threads. Thread (q=tid>>8, j=tid&255) holds whh bf16-packed
// for 3 gates x 128-c half-slice in 192 VGPRs. h f32 in LDS (broadcast reads);
// per step: 2-way partial reduce in LDS, 256 threads finish gates.
__global__ __launch_bounds__(512) void gru_kernel(
    const float* __restrict__ gi, const uint* __restrict__ P2,
    const float* __restrict__ bhh, const int* __restrict__ tsamp,
    float* __restrict__ c_t) {
  int b = blockIdx.x;
  int tid = threadIdx.x;
  int q = tid >> 8, j = tid & 255;
  __shared__ float hs[256];
  __shared__ float pr[512], pz[512], pn[512];
  uint W[192];
  {
    const uint* Pq = P2 + (size_t)q * 64 * 768 + j;
#pragma unroll
    for (int g = 0; g < 3; ++g)
#pragma unroll
      for (int cc = 0; cc < 64; ++cc)
        W[g * 64 + cc] = Pq[cc * 768 + g * 256];
  }
  if (tid < 256) hs[tid] = 0.f;
  int Tb = tsamp[b];
  float bhr = bhh[j], bhz = bhh[256 + j], bhn = bhh[512 + j];
  const float* gib = gi + (size_t)b * 256 * 768;
  __syncthreads();
  for (int t = 0; t <= Tb; ++t) {
    float xr_ = 0.f, xz_ = 0.f, xn_ = 0.f;
    if (tid < 256) {  // issue early; latency hides under the FMA loop
      const float* git = gib + t * 768;
      xr_ = git[j]; xz_ = git[256 + j]; xn_ = git[512 + j];
    }
    float2 ar = {0.f, 0.f}, az = {0.f, 0.f}, an = {0.f, 0.f};
    const float2* h2 = (const float2*)hs + q * 64;
#pragma unroll
    for (int cc = 0; cc < 64; ++cc) {
      float2 hh = h2[cc];
      uint ur = W[cc], uz = W[64 + cc], un = W[128 + cc];
      ar.x = fmaf(__uint_as_float(ur << 16), hh.x, ar.x);
      ar.y = fmaf(__uint_as_float(ur & 0xffff0000u), hh.y, ar.y);
      az.x = fmaf(__uint_as_float(uz << 16), hh.x, az.x);
      az.y = fmaf(__uint_as_float(uz & 0xffff0000u), hh.y, az.y);
      an.x = fmaf(__uint_as_float(un << 16), hh.x, an.x);
      an.y = fmaf(__uint_as_float(un & 0xffff0000u), hh.y, an.y);
    }
    pr[tid] = ar.x + ar.y;
    pz[tid] = az.x + az.y;
    pn[tid] = an.x + an.y;
    __syncthreads();
    if (tid < 256) {
      float sr = pr[j] + pr[j + 256];
      float sz = pz[j] + pz[j + 256];
      float sn = pn[j] + pn[j + 256];
      float r = 1.f / (1.f + __expf(-(xr_ + sr + bhr)));
      float zg = 1.f / (1.f + __expf(-(xz_ + sz + bhz)));
      float n = tanhf(fmaf(r, sn + bhn, xn_));
      float hj = hs[j];
      hs[j] = fmaf(zg, hj - n, n);  // (1-z)n + z*h
    }
    __syncthreads();
  }
  if (tid < 256) c_t[b * 256 + j] = hs[j];
}

// ---------------------------------------------------------------- pred
__global__ __launch_bounds__(256) void pred_kernel(
    const float* __restrict__ c_t, const float* __restrict__ wk,
    const float* __restrict__ bk, float* __restrict__ pred) {
  int tp = blockIdx.x >> 5, c = blockIdx.x & 31;
  __shared__ float cl[256];
  cl[threadIdx.x] = c_t[c * 256 + threadIdx.x];
  __syncthreads();
  const float* wkt = wk + (size_t)tp * 512 * 256;
  for (int d = threadIdx.x; d < 512; d += 256) {
    float a = bk[tp * 512 + d];
    const float* wv = wkt + (size_t)d * 256;
    for (int hh = 0; hh < 256; hh += 4) {
      float4 w4 = *(const float4*)&wv[hh];
      a = fmaf(w4.x, cl[hh], a);
      a = fmaf(w4.y, cl[hh + 1], a);
      a = fmaf(w4.z, cl[hh + 2], a);
      a = fmaf(w4.w, cl[hh + 3], a);
    }
    pred[((size_t)tp * 32 + c) * 512 + d] = a;
  }
}

// ---------------------------------------------------------------- totals
__global__ __launch_bounds__(256) void totals_kernel(
    const bf16* __restrict__ z5, const float* __restrict__ ab,
    const int* __restrict__ tsamp, const float* __restrict__ pred,
    float* __restrict__ totals) {
  int tp = blockIdx.x >> 5, b = blockIdx.x & 31;
  __shared__ float el[512];
  __shared__ float red[256];
  int tb = tsamp[b] + 1 + tp;
  for (int d = threadIdx.x; d < 512; d += 256) {
    float v = bf2f(z5[((size_t)b * 512 + d) * 256 + tb]);
    el[d] = fmaxf(fmaf(ab[d], v, ab[512 + d]), 0.f);
  }
  __syncthreads();
  int c = threadIdx.x & 31, chunk = threadIdx.x >> 5;
  const float* pr = pred + ((size_t)tp * 32 + c) * 512 + chunk * 64;
  const float* ep = &el[chunk * 64];
  float a = 0.f;
#pragma unroll 8
  for (int d = 0; d < 64; ++d) a = fmaf(pr[d], ep[d], a);
  red[threadIdx.x] = a;
  __syncthreads();
  if (threadIdx.x < 32) {
    float s = 0.f;
#pragma unroll
    for (int k = 0; k < 8; ++k) s += red[k * 32 + threadIdx.x];
    totals[((size_t)tp * 32 + b) * 32 + threadIdx.x] = s;
  }
}

// ---------------------------------------------------------------- final
__global__ __launch_bounds__(384) void final_kernel(const float* __restrict__ totals,
                                                    float* __restrict__ out) {
  __shared__ float adj[12 * 32 * 32];
  __shared__ float tr_red[384];
  __shared__ int cr_red[384];
  int tid = threadIdx.x;
  for (int i = tid; i < 12288; i += 384) adj[i] = totals[i];
  __syncthreads();
  int tp = tid / 32, b = tid % 32;
  float* row = &adj[(tp * 32 + b) * 32];
  float mx = row[0];
#pragma unroll
  for (int c = 1; c < 32; ++c) mx = fmaxf(mx, row[c]);
  float se = 0.f;
  for (int c = 0; c < 32; ++c) se += expf(row[c] - mx);
  float lse = mx + logf(se);
  float tr = row[b] - lse;
  __syncthreads();
  for (int c = 0; c < 32; ++c) row[c] -= lse;
  __syncthreads();
  int c = b;
  float best = adj[(tp * 32 + 0) * 32 + c];
  int bi = 0;
  for (int bb = 1; bb < 32; ++bb) {
    float v = adj[(tp * 32 + bb) * 32 + c];
    if (v > best) { best = v; bi = bb; }
  }
  tr_red[tid] = tr;
  cr_red[tid] = (bi == c) ? 1 : 0;
  __syncthreads();
  if (tid == 0) {
    float ts_ = 0.f;
    int cs = 0;
    for (int i = 0; i < 384; ++i) { ts_ += tr_red[i]; cs += cr_red[i]; }
    out[0] = (float)cs / 32.0f;
    out[1] = ts_ / (-384.0f);
  }
}

// ================================================================ launcher
extern "C" void kernel_launch(void* const* d_in, const int* in_sizes, int n_in,
                              void* d_out, int out_size, void* d_ws, size_t ws_size,
                              hipStream_t stream) {
  const float* x = (const float*)d_in[0];
  const int* tsamp = (const int*)d_in[1];
  const float* w1 = (const float*)d_in[2];
  const float* w2 = (const float*)d_in[3];
  const float* w3 = (const float*)d_in[4];
  const float* w4 = (const float*)d_in[5];
  const float* w5 = (const float*)d_in[6];
  const float* gg[5] = {(const float*)d_in[7], (const float*)d_in[9], (const float*)d_in[11],
                        (const float*)d_in[13], (const float*)d_in[15]};
  const float* bee[5] = {(const float*)d_in[8], (const float*)d_in[10], (const float*)d_in[12],
                         (const float*)d_in[14], (const float*)d_in[16]};
  const float* wih = (const float*)d_in[17];
  const float* whh = (const float*)d_in[18];
  const float* bih = (const float*)d_in[19];
  const float* bhh = (const float*)d_in[20];
  const float* wk = (const float*)d_in[21];
  const float* bk = (const float*)d_in[22];
  float* out = (float*)d_out;

  char* base = (char*)d_ws;
  size_t off = 0;
  auto alloc = [&](size_t bytes) -> char* {
    char* r = base + off;
    off = (off + bytes + 255) & ~(size_t)255;
    return r;
  };
  // S1: z1n chunk (67.2MB) -> z3raw -> gi.  S2: z2raw (67MB) -> z4raw.
  char* S1 = alloc((size_t)8 * 512 * 8208 * 2);
  char* S2 = alloc((size_t)32 * 512 * 2048 * 2);
  bf16* z1n = (bf16*)S1;
  bf16* z2r = (bf16*)S2;
  bf16* z3r = (bf16*)S1;
  bf16* z4r = (bf16*)S2;
  float* gi = (float*)S1;                             // 25.2MB
  bf16* z5 = (bf16*)alloc((size_t)4194304 * 2);
  bf16* wB2 = (bf16*)alloc((size_t)2097152 * 2);
  bf16* wB3 = (bf16*)alloc((size_t)1048576 * 2);
  bf16* wB4 = (bf16*)alloc((size_t)1048576 * 2);
  bf16* wB5 = (bf16*)alloc((size_t)1048576 * 2);
  float* wihT = (float*)alloc((size_t)393216 * 4);
  uint* whhP = (uint*)alloc((size_t)98304 * 4);
  float* stats = (float*)alloc(5 * 1024 * 4);
  float* ab = (float*)alloc(5 * 1024 * 4);
  float* ct = (float*)alloc(8192 * 4);
  float* pred = (float*)alloc(196608 * 4);
  float* totals = (float*)alloc(12288 * 4);
  (void)ws_size;

  hipMemsetAsync(stats, 0, 5 * 1024 * 4, stream);

  cvt_bf16_kernel<<<8192, 256, 0, stream>>>(w2, wB2, 2097152);
  cvt_bf16_kernel<<<4096, 256, 0, stream>>>(w3, wB3, 1048576);
  cvt_bf16_kernel<<<4096, 256, 0, stream>>>(w4, wB4, 1048576);
  cvt_bf16_kernel<<<4096, 256, 0, stream>>>(w5, wB5, 1048576);
  transpose_kernel<<<dim3(8, 12), 256, 0, stream>>>(wih, wihT, 768, 512);
  pack_whh_kernel<<<384, 256, 0, stream>>>(whh, whhP);

  stats1_kernel<<<dim3(16, 32), 256, 0, stream>>>(x, w1, stats);
  finalize_kernel<<<1, 512, 0, stream>>>(stats, gg[0], bee[0], 1.f / 262144.f, ab);

  for (int ch = 0; ch < 4; ++ch) {
    norm1_kernel<<<dim3(33, 8), 256, 0, stream>>>(x, w1, ab, z1n, ch * 8);
    conv2_mfma<<<dim3(16, 4, 8), 256, 0, stream>>>(z1n, wB2, z2r, ch * 8);
  }
  stats_kernel<<<16384, 256, 0, stream>>>(z2r, 2048, stats + 1024);
  finalize_kernel<<<1, 512, 0, stream>>>(stats + 1024, gg[1], bee[1], 1.f / 65536.f, ab + 1024);

  convN_mfma<<<dim3(8, 4, 32), 256, 0, stream>>>(z2r, wB3, ab + 1024, z3r, 2048, 1024);
  stats_kernel<<<16384, 256, 0, stream>>>(z3r, 1024, stats + 2048);
  finalize_kernel<<<1, 512, 0, stream>>>(stats + 2048, gg[2], bee[2], 1.f / 32768.f, ab + 2048);

  convN_mfma<<<dim3(4, 4, 32), 256, 0, stream>>>(z3r, wB4, ab + 2048, z4r, 1024, 512);
  stats_kernel<<<16384, 256, 0, stream>>>(z4r, 512, stats + 3072);
  finalize_kernel<<<1, 512, 0, stream>>>(stats + 3072, gg[3], bee[3], 1.f / 16384.f, ab + 3072);

  convN_mfma<<<dim3(2, 4, 32), 256, 0, stream>>>(z4r, wB5, ab + 3072, z5, 512, 256);
  stats_kernel<<<16384, 256, 0, stream>>>(z5, 256, stats + 4096);
  finalize_kernel<<<1, 512, 0, stream>>>(stats + 4096, gg[4], bee[4], 1.f / 8192.f, ab + 4096);

  gi_kernel<<<dim3(4, 6, 32), 256, 0, stream>>>(z5, wihT, bih, ab + 4096, gi);
  gru_kernel<<<32, 512, 0, stream>>>(gi, whhP, bhh, tsamp, ct);
  pred_kernel<<<384, 256, 0, stream>>>(ct, wk, bk, pred);
  totals_kernel<<<384, 256, 0, stream>>>(z5, ab + 4096, tsamp, pred, totals);
  final_kernel<<<1, 384, 0, stream>>>(totals, out);
}

// Round 10
// 4527.224 us; speedup vs baseline: 1.0329x; 1.0329x over previous
//
#include <hip/hip_runtime.h>
#include <hip/hip_bf16.h>

// CPC (CDCK2) round 8: GRU v3 — 1024 thr/block, 96 weight-uints/thread (no
// spill: fits 128-VGPR cap), 4-way LDS reduce. norm1 channel-split 8x.
// MFMA bf16 convs as round 5. B=32, L=40960, CH=512, H=256, T=12.

using bf16 = __hip_bfloat16;
typedef __attribute__((ext_vector_type(8))) short bf16x8;
typedef __attribute__((ext_vector_type(4))) float f32x4;

__device__ __forceinline__ float bf2f(bf16 v) { return __bfloat162float(v); }
__device__ __forceinline__ bf16 f2bf(float f) { return __float2bfloat16(f); }
__device__ __forceinline__ ushort bfbits(float f) {
  bf16 b = f2bf(f);
  return *reinterpret_cast<ushort*>(&b);
}
union FragU { uint4 u; bf16x8 v; };

// ---------------------------------------------------------------- stats1 (conv1 on the fly, x in LDS)
__global__ __launch_bounds__(256) void stats1_kernel(
    const float* __restrict__ x, const float* __restrict__ w1, float* __restrict__ sums) {
  __shared__ float xs[2576];
  int s = blockIdx.x, b = blockIdx.y;
  const float* xb = x + (size_t)b * 40960;
  int w0 = 2560 * s - 3;
  for (int i = threadIdx.x; i < 2565; i += 256) {
    int xi = w0 + i;
    xs[i] = ((unsigned)xi < 40960u) ? xb[xi] : 0.f;
  }
  __syncthreads();
  int c0 = threadIdx.x, c1 = threadIdx.x + 256;
  float wA[10], wB[10];
#pragma unroll
  for (int k = 0; k < 10; ++k) { wA[k] = w1[c0 * 10 + k]; wB[k] = w1[c1 * 10 + k]; }
  float sA = 0.f, qA = 0.f, sB = 0.f, qB = 0.f;
  for (int f = 0; f < 512; ++f) {
    const float* xp = &xs[5 * f];
    float aA = 0.f, aB = 0.f;
#pragma unroll
    for (int k = 0; k < 10; ++k) {
      float xv = xp[k];
      aA = fmaf(xv, wA[k], aA);
      aB = fmaf(xv, wB[k], aB);
    }
    sA += aA; qA = fmaf(aA, aA, qA);
    sB += aB; qB = fmaf(aB, aB, qB);
  }
  atomicAdd(&sums[c0], sA); atomicAdd(&sums[512 + c0], qA);
  atomicAdd(&sums[c1], sB); atomicAdd(&sums[512 + c1], qB);
}

// ---------------------------------------------------------------- BN stats (bf16 z)
__global__ __launch_bounds__(256) void stats_kernel(
    const bf16* __restrict__ z, int F, float* __restrict__ sums) {
  int bc = blockIdx.x;
  int c = bc & 511;
  const bf16* p = z + (size_t)bc * F;
  float s = 0.f, q = 0.f;
  for (int i = threadIdx.x; i < F; i += 256) {
    float v = bf2f(p[i]);
    s += v;
    q = fmaf(v, v, q);
  }
  __shared__ float rs[256], rq[256];
  rs[threadIdx.x] = s; rq[threadIdx.x] = q;
  __syncthreads();
  for (int w = 128; w > 0; w >>= 1) {
    if (threadIdx.x < w) {
      rs[threadIdx.x] += rs[threadIdx.x + w];
      rq[threadIdx.x] += rq[threadIdx.x + w];
    }
    __syncthreads();
  }
  if (threadIdx.x == 0) {
    atomicAdd(&sums[c], rs[0]);
    atomicAdd(&sums[512 + c], rq[0]);
  }
}

__global__ void finalize_kernel(const float* __restrict__ sums, const float* __restrict__ g,
                                const float* __restrict__ be, float invN,
                                float* __restrict__ ab) {
  int c = threadIdx.x;  // 512
  float mean = sums[c] * invN;
  float var = fmaf(-mean, mean, sums[512 + c] * invN);
  float a = g[c] * rsqrtf(var + 1e-5f);
  ab[c] = a;
  ab[512 + c] = fmaf(-mean, a, be[c]);
}

// ---------------------------------------------------------------- transpose (wih only)
__global__ __launch_bounds__(256) void transpose_kernel(
    const float* __restrict__ in, float* __restrict__ out, int R, int C) {
  __shared__ float t[64][65];
  int c0 = blockIdx.x * 64, r0 = blockIdx.y * 64;
  int tx = threadIdx.x & 63, ty = threadIdx.x >> 6;
  for (int i = ty; i < 64; i += 4) {
    int r = r0 + i, c = c0 + tx;
    t[i][tx] = (r < R && c < C) ? in[(size_t)r * C + c] : 0.f;
  }
  __syncthreads();
  for (int i = ty; i < 64; i += 4) {
    int c = c0 + i, r = r0 + tx;
    if (c < C && r < R) out[(size_t)c * R + r] = t[tx][i];
  }
}

__global__ void cvt_bf16_kernel(const float* __restrict__ in, bf16* __restrict__ out, int n) {
  int i = blockIdx.x * 256 + threadIdx.x;
  if (i < n) out[i] = f2bf(in[i]);
}

// pack whh for GRU v3: P3[(q*32+cc)*768 + gj] = pack2(whh[gj][64q+2cc], whh[gj][64q+2cc+1])
__global__ void pack_whh_kernel(const float* __restrict__ whh, uint* __restrict__ P3) {
  int idx = blockIdx.x * 256 + threadIdx.x;
  if (idx < 98304) {
    int qcc = idx / 768, gj = idx % 768;
    int q = qcc >> 5, cc = qcc & 31;
    int c0 = 64 * q + 2 * cc;
    float lo = whh[(size_t)gj * 256 + c0];
    float hi = whh[(size_t)gj * 256 + c0 + 1];
    P3[idx] = (uint)bfbits(lo) | ((uint)bfbits(hi) << 16);
  }
}

// ---------------------------------------------------------------- norm1 (conv1+BN1+ReLU -> padded bf16)
// grid (33 pslices, 8 b, 8 cslices); zn: [8 b][512 c][8208], data at 6+fi.
__global__ __launch_bounds__(256) void norm1_kernel(
    const float* __restrict__ x, const float* __restrict__ w1,
    const float* __restrict__ ab, bf16* __restrict__ zn, int chunk0) {
  __shared__ float xs[1312];
  int s = blockIdx.x, bl = blockIdx.y, cs = blockIdx.z;
  int pidx = s * 256 + threadIdx.x;
  const float* xb = x + (size_t)(chunk0 + bl) * 40960;
  int w0 = 1280 * s - 33;
  for (int i = threadIdx.x; i < 1285; i += 256) {
    int xi = w0 + i;
    xs[i] = ((unsigned)xi < 40960u) ? xb[xi] : 0.f;
  }
  __syncthreads();
  if (pidx >= 8208) return;
  int fi = pidx - 6;
  bool inb = ((unsigned)fi < 8192u);
  const float* xp = &xs[5 * threadIdx.x];
  bf16* zp = zn + (size_t)bl * 512 * 8208 + pidx;
  for (int c = cs * 64; c < cs * 64 + 64; ++c) {
    float v = 0.f;
    if (inb) {
      float acc = 0.f;
      const float* w = &w1[c * 10];
#pragma unroll
      for (int k = 0; k < 10; ++k) acc = fmaf(xp[k], w[k], acc);
      v = fmaxf(fmaf(ab[c], acc, ab[512 + c]), 0.f);
    }
    zp[(size_t)c * 8208] = f2bf(v);
  }
}

// ---------------------------------------------------------------- conv2 MFMA
__global__ __launch_bounds__(256) void conv2_mfma(
    const bf16* __restrict__ zn, const bf16* __restrict__ wB,
    bf16* __restrict__ out, int chunk0) {
  __shared__ ushort aL[4][520];
  __shared__ ushort bL[128][36];
  int fo0 = blockIdx.x * 128, co0 = blockIdx.y * 128, bl = blockIdx.z;
  int tid = threadIdx.x;
  int w = tid >> 6, l = tid & 63;
  int m0 = (w >> 1) * 64, n0 = (w & 1) * 64;
  int row = l & 15, kq = l >> 4;
  f32x4 acc[4][4];
#pragma unroll
  for (int i = 0; i < 4; ++i)
#pragma unroll
    for (int j = 0; j < 4; ++j) acc[i][j] = {0.f, 0.f, 0.f, 0.f};
  const ushort* zb = (const ushort*)zn + (size_t)bl * 512 * 8208;
  int astart = 4 * fo0 + 4;
  int sco = tid >> 1, shalf = tid & 1;
  for (int step = 0; step < 128; ++step) {
    int ci0 = step * 4;
    int k0 = step * 32;
    __syncthreads();
    for (int u = tid; u < 520; u += 256) {
      int ci = u / 130, off = (u % 130) * 4;
      *(uint2*)&aL[ci][off] =
          *(const uint2*)(zb + (size_t)(ci0 + ci) * 8208 + astart + off);
    }
    {
      const uint2* src = (const uint2*)(wB + (size_t)(co0 + sco) * 4096 + k0 + shalf * 16);
      uint2* dst = (uint2*)&bL[sco][shalf * 16];
      dst[0] = src[0]; dst[1] = src[1]; dst[2] = src[2]; dst[3] = src[3];
    }
    __syncthreads();
    bf16x8 af[4], bfr[4];
#pragma unroll
    for (int mi = 0; mi < 4; ++mi) {
      int am = (m0 + mi * 16 + row) * 4;
      const uint2* ap = (const uint2*)((const char*)&aL[0][0] + kq * 1040 + am * 2);
      uint2 a0 = ap[0], a1 = ap[1];
      FragU f; f.u = make_uint4(a0.x, a0.y, a1.x, a1.y);
      af[mi] = f.v;
    }
#pragma unroll
    for (int ni = 0; ni < 4; ++ni) {
      int col = n0 + ni * 16 + row;
      const uint2* bp = (const uint2*)((const char*)&bL[0][0] + col * 72 + kq * 16);
      uint2 b0 = bp[0], b1 = bp[1];
      FragU f; f.u = make_uint4(b0.x, b0.y, b1.x, b1.y);
      bfr[ni] = f.v;
    }
#pragma unroll
    for (int mi = 0; mi < 4; ++mi)
#pragma unroll
      for (int ni = 0; ni < 4; ++ni)
        acc[mi][ni] = __builtin_amdgcn_mfma_f32_16x16x32_bf16(af[mi], bfr[ni], acc[mi][ni], 0, 0, 0);
  }
  size_t ob = (size_t)(chunk0 + bl) * 512;
#pragma unroll
  for (int mi = 0; mi < 4; ++mi)
#pragma unroll
    for (int ni = 0; ni < 4; ++ni)
#pragma unroll
      for (int r = 0; r < 4; ++r) {
        int m = m0 + mi * 16 + kq * 4 + r;
        int n = n0 + ni * 16 + row;
        out[(ob + co0 + n) * 2048 + fo0 + m] = f2bf(acc[mi][ni][r]);
      }
}

// ---------------------------------------------------------------- convN MFMA (K=4,S=2,P=1; layers 3-5)
__global__ __launch_bounds__(256) void convN_mfma(
    const bf16* __restrict__ in, const bf16* __restrict__ wB,
    const float* __restrict__ ab, bf16* __restrict__ out, int Fi, int Fo) {
  __shared__ ushort aL[8][264];
  __shared__ ushort bL[128][36];
  int fo0 = blockIdx.x * 128, co0 = blockIdx.y * 128, b = blockIdx.z;
  int tid = threadIdx.x;
  int w = tid >> 6, l = tid & 63;
  int m0 = (w >> 1) * 64, n0 = (w & 1) * 64;
  int row = l & 15, kq = l >> 4;
  f32x4 acc[4][4];
#pragma unroll
  for (int i = 0; i < 4; ++i)
#pragma unroll
    for (int j = 0; j < 4; ++j) acc[i][j] = {0.f, 0.f, 0.f, 0.f};
  int fi0 = fo0 * 2 - 1;
  const bf16* ib = in + (size_t)b * 512 * Fi;
  int sco = tid >> 1, shalf = tid & 1;
  for (int step = 0; step < 64; ++step) {
    int ci0 = step * 8;
    int k0 = step * 32;
    __syncthreads();
    for (int u = tid; u < 1032; u += 256) {
      int ci = u / 129, pp = (u % 129) * 2;
      float a = ab[ci0 + ci], bb = ab[512 + ci0 + ci];
      const bf16* zr = ib + (size_t)(ci0 + ci) * Fi;
      uint pk = 0;
#pragma unroll
      for (int e = 0; e < 2; ++e) {
        int fi = fi0 + pp + e;
        float v = 0.f;
        if ((unsigned)fi < (unsigned)Fi)
          v = fmaxf(fmaf(a, bf2f(zr[fi]), bb), 0.f);
        pk |= (uint)bfbits(v) << (16 * e);
      }
      *(uint*)&aL[ci][pp] = pk;
    }
    {
      const uint2* src = (const uint2*)(wB + (size_t)(co0 + sco) * 2048 + k0 + shalf * 16);
      uint2* dst = (uint2*)&bL[sco][shalf * 16];
      dst[0] = src[0]; dst[1] = src[1]; dst[2] = src[2]; dst[3] = src[3];
    }
    __syncthreads();
    bf16x8 af[4], bfr[4];
#pragma unroll
    for (int mi = 0; mi < 4; ++mi) {
      int p0 = (m0 + mi * 16 + row) * 2;
      const char* base = (const char*)&aL[0][0];
      const uint* r0p = (const uint*)(base + (2 * kq) * 528 + p0 * 2);
      const uint* r1p = (const uint*)(base + (2 * kq + 1) * 528 + p0 * 2);
      FragU f; f.u = make_uint4(r0p[0], r0p[1], r1p[0], r1p[1]);
      af[mi] = f.v;
    }
#pragma unroll
    for (int ni = 0; ni < 4; ++ni) {
      int col = n0 + ni * 16 + row;
      const uint2* bp = (const uint2*)((const char*)&bL[0][0] + col * 72 + kq * 16);
      uint2 b0 = bp[0], b1 = bp[1];
      FragU f; f.u = make_uint4(b0.x, b0.y, b1.x, b1.y);
      bfr[ni] = f.v;
    }
#pragma unroll
    for (int mi = 0; mi < 4; ++mi)
#pragma unroll
      for (int ni = 0; ni < 4; ++ni)
        acc[mi][ni] = __builtin_amdgcn_mfma_f32_16x16x32_bf16(af[mi], bfr[ni], acc[mi][ni], 0, 0, 0);
  }
  size_t ob = (size_t)b * 512;
#pragma unroll
  for (int mi = 0; mi < 4; ++mi)
#pragma unroll
    for (int ni = 0; ni < 4; ++ni)
#pragma unroll
      for (int r = 0; r < 4; ++r) {
        int m = m0 + mi * 16 + kq * 4 + r;
        int n = n0 + ni * 16 + row;
        out[(ob + co0 + n) * Fo + fo0 + m] = f2bf(acc[mi][ni][r]);
      }
}

// ---------------------------------------------------------------- gi GEMM (VALU, small)
__global__ __launch_bounds__(256) void gi_kernel(
    const bf16* __restrict__ z5, const float* __restrict__ wihT,
    const float* __restrict__ bih, const float* __restrict__ ab,
    float* __restrict__ gi) {
  __shared__ float a_lds[8][64];
  __shared__ float w_lds[8][128];
  int t0 = blockIdx.x * 64, j0 = blockIdx.y * 128, b = blockIdx.z;
  int tid = threadIdx.x, tx = tid & 15, ty = tid >> 4;
  float acc[4][8] = {};
  for (int ci0 = 0; ci0 < 512; ci0 += 8) {
    __syncthreads();
    for (int i = tid; i < 512; i += 256) {
      int ci = i >> 6, t = i & 63;
      float v = bf2f(z5[((size_t)b * 512 + ci0 + ci) * 256 + t0 + t]);
      a_lds[ci][t] = fmaxf(fmaf(ab[ci0 + ci], v, ab[512 + ci0 + ci]), 0.f);
    }
    {
      int i = tid * 4;
      int ci = i >> 7, j = i & 127;
      *(float4*)&w_lds[ci][j] = *(const float4*)&wihT[(size_t)(ci0 + ci) * 768 + j0 + j];
    }
    __syncthreads();
#pragma unroll
    for (int ci = 0; ci < 8; ++ci) {
      float av[4];
#pragma unroll
      for (int j = 0; j < 4; ++j) av[j] = a_lds[ci][tx + 16 * j];
      const float* wp = &w_lds[ci][ty * 8];
      float4 w0 = *(const float4*)wp;
      float4 w1 = *(const float4*)(wp + 4);
      float wv[8] = {w0.x, w0.y, w0.z, w0.w, w1.x, w1.y, w1.z, w1.w};
#pragma unroll
      for (int j = 0; j < 4; ++j)
#pragma unroll
        for (int cc = 0; cc < 8; ++cc)
          acc[j][cc] = fmaf(av[j], wv[cc], acc[j][cc]);
    }
  }
  float bv[8];
#pragma unroll
  for (int cc = 0; cc < 8; ++cc) bv[cc] = bih[j0 + ty * 8 + cc];
#pragma unroll
  for (int j = 0; j < 4; ++j) {
    int rowi = t0 + tx + 16 * j;
    float4 s0 = {acc[j][0] + bv[0], acc[j][1] + bv[1], acc[j][2] + bv[2], acc[j][3] + bv[3]};
    float4 s1 = {acc[j][4] + bv[4], acc[j][5] + bv[5], acc[j][6] + bv[6], acc[j][7] + bv[7]};
    float* gp = &gi[((size_t)b * 256 + rowi) * 768 + j0 + ty * 8];
    *(float4*)gp = s0;
    *(float4*)(gp + 4) = s1;
  }
}

// ---------------------------------------------------------------- GRU v3
// 32 blocks x 1024 threads. Thread (q=tid>>8, j=tid&255) holds whh bf16-packed
// for 3 gates x 64-c quarter-slice in 96 VGPRs (fits 128-cap, no spill).
// h f32 in LDS (broadcast reads); 4-way partial reduce; 256 threads finish.
__global__ __launch_bounds__(1024) void gru_kernel(
    const float* __restrict__ gi, const uint* __restrict__ P3,
    const float* __restrict__ bhh, const int* __restrict__ tsamp,
    float* __restrict__ c_t) {
  int b = blockIdx.x;
  int tid = threadIdx.x;
  int q = tid >> 8, j = tid & 255;
  __shared__ float hs[256];
  __shared__ float pr[1024], pz[1024], pn[1024];
  uint W[96];
  {
    const uint* Pq = P3 + (size_t)q * 32 * 768 + j;
#pragma unroll
    for (int g = 0; g < 3; ++g)
#pragma unroll
      for (int cc = 0; cc < 32; ++cc)
        W[g * 32 + cc] = Pq[cc * 768 + g * 256];
  }
  if (tid < 256) hs[tid] = 0.f;
  int Tb = tsamp[b];
  float bhr = bhh[j], bhz = bhh[256 + j], bhn = bhh[512 + j];
  const float* gib = gi + (size_t)b * 256 * 768;
  __syncthreads();
  for (int t = 0; t <= Tb; ++t) {
    float xr_ = 0.f, xz_ = 0.f, xn_ = 0.f;
    if (tid < 256) {  // issue early; latency hides under the FMA loop
      const float* git = gib + t * 768;
      xr_ = git[j]; xz_ = git[256 + j]; xn_ = git[512 + j];
    }
    float2 ar = {0.f, 0.f}, az = {0.f, 0.f}, an = {0.f, 0.f};
    const float2* h2 = (const float2*)hs + q * 32;
#pragma unroll
    for (int cc = 0; cc < 32; ++cc) {
      float2 hh = h2[cc];
      uint ur = W[cc], uz = W[32 + cc], un = W[64 + cc];
      ar.x = fmaf(__uint_as_float(ur << 16), hh.x, ar.x);
      ar.y = fmaf(__uint_as_float(ur & 0xffff0000u), hh.y, ar.y);
      az.x = fmaf(__uint_as_float(uz << 16), hh.x, az.x);
      az.y = fmaf(__uint_as_float(uz & 0xffff0000u), hh.y, az.y);
      an.x = fmaf(__uint_as_float(un << 16), hh.x, an.x);
      an.y = fmaf(__uint_as_float(un & 0xffff0000u), hh.y, an.y);
    }
    pr[tid] = ar.x + ar.y;
    pz[tid] = az.x + az.y;
    pn[tid] = an.x + an.y;
    __syncthreads();
    if (tid < 256) {
      float sr = pr[j] + pr[j + 256] + pr[j + 512] + pr[j + 768];
      float sz = pz[j] + pz[j + 256] + pz[j + 512] + pz[j + 768];
      float sn = pn[j] + pn[j + 256] + pn[j + 512] + pn[j + 768];
      float r = 1.f / (1.f + __expf(-(xr_ + sr + bhr)));
      float zg = 1.f / (1.f + __expf(-(xz_ + sz + bhz)));
      float n = tanhf(fmaf(r, sn + bhn, xn_));
      float hj = hs[j];
      hs[j] = fmaf(zg, hj - n, n);  // (1-z)n + z*h
    }
    __syncthreads();
  }
  if (tid < 256) c_t[b * 256 + j] = hs[j];
}

// ---------------------------------------------------------------- pred
__global__ __launch_bounds__(256) void pred_kernel(
    const float* __restrict__ c_t, const float* __restrict__ wk,
    const float* __restrict__ bk, float* __restrict__ pred) {
  int tp = blockIdx.x >> 5, c = blockIdx.x & 31;
  __shared__ float cl[256];
  cl[threadIdx.x] = c_t[c * 256 + threadIdx.x];
  __syncthreads();
  const float* wkt = wk + (size_t)tp * 512 * 256;
  for (int d = threadIdx.x; d < 512; d += 256) {
    float a = bk[tp * 512 + d];
    const float* wv = wkt + (size_t)d * 256;
    for (int hh = 0; hh < 256; hh += 4) {
      float4 w4 = *(const float4*)&wv[hh];
      a = fmaf(w4.x, cl[hh], a);
      a = fmaf(w4.y, cl[hh + 1], a);
      a = fmaf(w4.z, cl[hh + 2], a);
      a = fmaf(w4.w, cl[hh + 3], a);
    }
    pred[((size_t)tp * 32 + c) * 512 + d] = a;
  }
}

// ---------------------------------------------------------------- totals
__global__ __launch_bounds__(256) void totals_kernel(
    const bf16* __restrict__ z5, const float* __restrict__ ab,
    const int* __restrict__ tsamp, const float* __restrict__ pred,
    float* __restrict__ totals) {
  int tp = blockIdx.x >> 5, b = blockIdx.x & 31;
  __shared__ float el[512];
  __shared__ float red[256];
  int tb = tsamp[b] + 1 + tp;
  for (int d = threadIdx.x; d < 512; d += 256) {
    float v = bf2f(z5[((size_t)b * 512 + d) * 256 + tb]);
    el[d] = fmaxf(fmaf(ab[d], v, ab[512 + d]), 0.f);
  }
  __syncthreads();
  int c = threadIdx.x & 31, chunk = threadIdx.x >> 5;
  const float* pr = pred + ((size_t)tp * 32 + c) * 512 + chunk * 64;
  const float* ep = &el[chunk * 64];
  float a = 0.f;
#pragma unroll 8
  for (int d = 0; d < 64; ++d) a = fmaf(pr[d], ep[d], a);
  red[threadIdx.x] = a;
  __syncthreads();
  if (threadIdx.x < 32) {
    float s = 0.f;
#pragma unroll
    for (int k = 0; k < 8; ++k) s += red[k * 32 + threadIdx.x];
    totals[((size_t)tp * 32 + b) * 32 + threadIdx.x] = s;
  }
}

// ---------------------------------------------------------------- final
__global__ __launch_bounds__(384) void final_kernel(const float* __restrict__ totals,
                                                    float* __restrict__ out) {
  __shared__ float adj[12 * 32 * 32];
  __shared__ float tr_red[384];
  __shared__ int cr_red[384];
  int tid = threadIdx.x;
  for (int i = tid; i < 12288; i += 384) adj[i] = totals[i];
  __syncthreads();
  int tp = tid / 32, b = tid % 32;
  float* row = &adj[(tp * 32 + b) * 32];
  float mx = row[0];
#pragma unroll
  for (int c = 1; c < 32; ++c) mx = fmaxf(mx, row[c]);
  float se = 0.f;
  for (int c = 0; c < 32; ++c) se += expf(row[c] - mx);
  float lse = mx + logf(se);
  float tr = row[b] - lse;
  __syncthreads();
  for (int c = 0; c < 32; ++c) row[c] -= lse;
  __syncthreads();
  int c = b;
  float best = adj[(tp * 32 + 0) * 32 + c];
  int bi = 0;
  for (int bb = 1; bb < 32; ++bb) {
    float v = adj[(tp * 32 + bb) * 32 + c];
    if (v > best) { best = v; bi = bb; }
  }
  tr_red[tid] = tr;
  cr_red[tid] = (bi == c) ? 1 : 0;
  __syncthreads();
  if (tid == 0) {
    float ts_ = 0.f;
    int cs = 0;
    for (int i = 0; i < 384; ++i) { ts_ += tr_red[i]; cs += cr_red[i]; }
    out[0] = (float)cs / 32.0f;
    out[1] = ts_ / (-384.0f);
  }
}

// ================================================================ launcher
extern "C" void kernel_launch(void* const* d_in, const int* in_sizes, int n_in,
                              void* d_out, int out_size, void* d_ws, size_t ws_size,
                              hipStream_t stream) {
  const float* x = (const float*)d_in[0];
  const int* tsamp = (const int*)d_in[1];
  const float* w1 = (const float*)d_in[2];
  const float* w2 = (const float*)d_in[3];
  const float* w3 = (const float*)d_in[4];
  const float* w4 = (const float*)d_in[5];
  const float* w5 = (const float*)d_in[6];
  const float* gg[5] = {(const float*)d_in[7], (const float*)d_in[9], (const float*)d_in[11],
                        (const float*)d_in[13], (const float*)d_in[15]};
  const float* bee[5] = {(const float*)d_in[8], (const float*)d_in[10], (const float*)d_in[12],
                         (const float*)d_in[14], (const float*)d_in[16]};
  const float* wih = (const float*)d_in[17];
  const float* whh = (const float*)d_in[18];
  const float* bih = (const float*)d_in[19];
  const float* bhh = (const float*)d_in[20];
  const float* wk = (const float*)d_in[21];
  const float* bk = (const float*)d_in[22];
  float* out = (float*)d_out;

  char* base = (char*)d_ws;
  size_t off = 0;
  auto alloc = [&](size_t bytes) -> char* {
    char* r = base + off;
    off = (off + bytes + 255) & ~(size_t)255;
    return r;
  };
  // S1: z1n chunk (67.2MB) -> z3raw -> gi.  S2: z2raw (67MB) -> z4raw.
  char* S1 = alloc((size_t)8 * 512 * 8208 * 2);
  char* S2 = alloc((size_t)32 * 512 * 2048 * 2);
  bf16* z1n = (bf16*)S1;
  bf16* z2r = (bf16*)S2;
  bf16* z3r = (bf16*)S1;
  bf16* z4r = (bf16*)S2;
  float* gi = (float*)S1;                             // 25.2MB
  bf16* z5 = (bf16*)alloc((size_t)4194304 * 2);
  bf16* wB2 = (bf16*)alloc((size_t)2097152 * 2);
  bf16* wB3 = (bf16*)alloc((size_t)1048576 * 2);
  bf16* wB4 = (bf16*)alloc((size_t)1048576 * 2);
  bf16* wB5 = (bf16*)alloc((size_t)1048576 * 2);
  float* wihT = (float*)alloc((size_t)393216 * 4);
  uint* whhP = (uint*)alloc((size_t)98304 * 4);
  float* stats = (float*)alloc(5 * 1024 * 4);
  float* ab = (float*)alloc(5 * 1024 * 4);
  float* ct = (float*)alloc(8192 * 4);
  float* pred = (float*)alloc(196608 * 4);
  float* totals = (float*)alloc(12288 * 4);
  (void)ws_size;

  hipMemsetAsync(stats, 0, 5 * 1024 * 4, stream);

  cvt_bf16_kernel<<<8192, 256, 0, stream>>>(w2, wB2, 2097152);
  cvt_bf16_kernel<<<4096, 256, 0, stream>>>(w3, wB3, 1048576);
  cvt_bf16_kernel<<<4096, 256, 0, stream>>>(w4, wB4, 1048576);
  cvt_bf16_kernel<<<4096, 256, 0, stream>>>(w5, wB5, 1048576);
  transpose_kernel<<<dim3(8, 12), 256, 0, stream>>>(wih, wihT, 768, 512);
  pack_whh_kernel<<<384, 256, 0, stream>>>(whh, whhP);

  stats1_kernel<<<dim3(16, 32), 256, 0, stream>>>(x, w1, stats);
  finalize_kernel<<<1, 512, 0, stream>>>(stats, gg[0], bee[0], 1.f / 262144.f, ab);

  for (int ch = 0; ch < 4; ++ch) {
    norm1_kernel<<<dim3(33, 8, 8), 256, 0, stream>>>(x, w1, ab, z1n, ch * 8);
    conv2_mfma<<<dim3(16, 4, 8), 256, 0, stream>>>(z1n, wB2, z2r, ch * 8);
  }
  stats_kernel<<<16384, 256, 0, stream>>>(z2r, 2048, stats + 1024);
  finalize_kernel<<<1, 512, 0, stream>>>(stats + 1024, gg[1], bee[1], 1.f / 65536.f, ab + 1024);

  convN_mfma<<<dim3(8, 4, 32), 256, 0, stream>>>(z2r, wB3, ab + 1024, z3r, 2048, 1024);
  stats_kernel<<<16384, 256, 0, stream>>>(z3r, 1024, stats + 2048);
  finalize_kernel<<<1, 512, 0, stream>>>(stats + 2048, gg[2], bee[2], 1.f / 32768.f, ab + 2048);

  convN_mfma<<<dim3(4, 4, 32), 256, 0, stream>>>(z3r, wB4, ab + 2048, z4r, 1024, 512);
  stats_kernel<<<16384, 256, 0, stream>>>(z4r, 512, stats + 3072);
  finalize_kernel<<<1, 512, 0, stream>>>(stats + 3072, gg[3], bee[3], 1.f / 16384.f, ab + 3072);

  convN_mfma<<<dim3(2, 4, 32), 256, 0, stream>>>(z4r, wB5, ab + 3072, z5, 512, 256);
  stats_kernel<<<16384, 256, 0, stream>>>(z5, 256, stats + 4096);
  finalize_kernel<<<1, 512, 0, stream>>>(stats + 4096, gg[4], bee[4], 1.f / 8192.f, ab + 4096);

  gi_kernel<<<dim3(4, 6, 32), 256, 0, stream>>>(z5, wihT, bih, ab + 4096, gi);
  gru_kernel<<<32, 1024, 0, stream>>>(gi, whhP, bhh, tsamp, ct);
  pred_kernel<<<384, 256, 0, stream>>>(ct, wk, bk, pred);
  totals_kernel<<<384, 256, 0, stream>>>(z5, ab + 4096, tsamp, pred, totals);
  final_kernel<<<1, 384, 0, stream>>>(totals, out);
}